// Round 7
// baseline (408.173 us; speedup 1.0000x reference)
//
#include <hip/hip_runtime.h>

#define NTAG 128
#define SEQ 512
#define NBATCH 512
#define END_ID 1

typedef _Float16 h2 __attribute__((ext_vector_type(2)));
typedef __fp16 fp16x2 __attribute__((ext_vector_type(2)));
typedef uint u32x32 __attribute__((ext_vector_type(32)));

#define LOG2E 1.4426950408889634f
#define LN2   0.6931471805599453f

__device__ __forceinline__ float bcast0(float v) {
  return __int_as_float(__builtin_amdgcn_readfirstlane(__float_as_int(v)));
}
__device__ __forceinline__ uint pack2(float a, float b) {
  fp16x2 h = __builtin_amdgcn_cvt_pkrtz(a, b);
  return __builtin_bit_cast(uint, h);
}
__device__ __forceinline__ h2 as_h2(uint u) { return __builtin_bit_cast(h2, u); }

__device__ __forceinline__ float fast_exp2(float x) {
#if __has_builtin(__builtin_amdgcn_exp2f)
  return __builtin_amdgcn_exp2f(x);
#else
  return exp2f(x);
#endif
}
__device__ __forceinline__ float fast_log2(float x) {
#if __has_builtin(__builtin_amdgcn_logf)
  return __builtin_amdgcn_logf(x);
#else
  return log2f(x);
#endif
}

#if __has_builtin(__builtin_amdgcn_fdot2)
#define FDOT2(pu, eu, acc) acc = __builtin_amdgcn_fdot2(as_h2(pu), as_h2(eu), acc, false)
#else
#define FDOT2(pu, eu, acc) do { h2 _p = as_h2(pu), _e = as_h2(eu); \
  acc = fmaf((float)_p.x, (float)_e.x, fmaf((float)_p.y, (float)_e.y, acc)); } while (0)
#endif

// TWO WAVES per batch (block=128, thread tid = tag). Wall time = len_max x
// per-step LATENCY (straggler-bound), so this halves per-wave dot work
// (64 FDOT2) and kills the readlane/SGPR path that stalled rounds 4-6.
// Per step: per-wave shift M_w = readfirstlane(A) (no cross-wave sync; the
// halves are combined EXACTLY with one exp2(M1-M0) factor); p -> f16
// ds_write_b16 into a DOUBLE-BUFFERED p array (one barrier/step, no WAR
// barrier); 16 uniform ds_read_b128 (broadcast, conflict-free); 4 dot
// chains; log2-domain update (v_exp/v_log are base-2 natively).
// E' = exp2(trans*log2e) f16 pairs: 64 VGPRs/lane (arch-VGPR, no AGPR risk).
__global__ __launch_bounds__(128, 1) void crf_kernel(
    const float* __restrict__ x,      // [B,S,T]
    const int*   __restrict__ tags,   // [B,S]
    const float* __restrict__ mask,   // [B,S]
    const float* __restrict__ trans,  // [T,T]
    float* __restrict__ ws)           // [B]
{
  const int b    = blockIdx.x;
  const int tid  = threadIdx.x;       // 0..127 = tag j
  const int lane = tid & 63;
  const int wv   = tid >> 6;          // wave 0: tags 0..63, wave 1: 64..127

  __shared__ alignas(16) _Float16 p_lds[2][NTAG];  // double-buffered p (f16)
  __shared__ float m_lds[2][2];                     // per-wave shifts
  __shared__ float red[4];

  const float* xb   = x    + (size_t)b * SEQ * NTAG;
  const float* mrow = mask + (size_t)b * SEQ;
  const int*   trow = tags + (size_t)b * SEQ;

  // ---- len = sum(mask row); mask is exact 0.0/1.0, monotonic ----
  float msum = 0.f;
  #pragma unroll
  for (int i = 0; i < SEQ / 128; ++i) msum += mrow[tid + i * 128];
  #pragma unroll
  for (int off = 1; off < 64; off <<= 1) msum += __shfl_xor(msum, off);
  if (lane == 0) red[wv] = msum;
  __syncthreads();
  const int len = (int)(red[0] + red[1]);   // in [1, 510]
  __syncthreads();

  // ---- E' row tid: exp2(trans[tid][k]*log2e), f16 pairs, 64 VGPRs ----
  u32x32 eA, eB;                      // k-pair kp: kp<32 -> eA[kp], else eB
  {
    const float4* r = (const float4*)(trans + (size_t)tid * NTAG);
    #pragma unroll
    for (int k4 = 0; k4 < 16; ++k4) {
      float4 f = r[k4];
      eA[2 * k4 + 0] = pack2(fast_exp2(f.x * LOG2E), fast_exp2(f.y * LOG2E));
      eA[2 * k4 + 1] = pack2(fast_exp2(f.z * LOG2E), fast_exp2(f.w * LOG2E));
    }
    #pragma unroll
    for (int k4 = 16; k4 < 32; ++k4) {
      float4 f = r[k4];
      eB[2 * (k4 - 16) + 0] = pack2(fast_exp2(f.x * LOG2E), fast_exp2(f.y * LOG2E));
      eB[2 * (k4 - 16) + 1] = pack2(fast_exp2(f.z * LOG2E), fast_exp2(f.w * LOG2E));
    }
  }

  // log2-domain alpha; per-wave shifts handle the -inf init exactly:
  // wave1's p's are relative to M1=-14427 and get scaled by 2^(M1-M0)=0.
  float A  = (tid == 0) ? 0.f : -14427.f;   // -1e4*log2e (START_ID=0)
  float xt = xb[tid];                        // x[b][0][tid]

  for (int t = 0; t < len; ++t) {
    const int buf = t & 1;
    const float Mw = bcast0(A);              // per-wave shift (SGPR)
    const float p  = fminf(fast_exp2(A - Mw), 60000.f);
    p_lds[buf][tid] = (_Float16)p;           // ds_write_b16 (2-way: free)
    if (lane == 0) m_lds[buf][wv] = Mw;

    // prefetch next emission (t+1 <= len <= 510 < SEQ), coalesced
    const float xn = xb[(size_t)(t + 1) * NTAG + tid];

    __syncthreads();                         // single barrier per step

    const float2 mv = *(const float2*)m_lds[buf];   // M0, M1 (broadcast)
    const uint4* p4 = (const uint4*)p_lds[buf];     // uniform => broadcast

    float a0 = 0.f, a1 = 0.f, b0 = 0.f, b1 = 0.f;  // 4 chains, depth 16
    #pragma unroll
    for (int c = 0; c < 8; ++c) {            // k-pairs 4c..4c+3 (k < 64)
      uint4 pv = p4[c];
      FDOT2(pv.x, eA[4 * c + 0], a0);
      FDOT2(pv.y, eA[4 * c + 1], a1);
      FDOT2(pv.z, eA[4 * c + 2], a0);
      FDOT2(pv.w, eA[4 * c + 3], a1);
    }
    #pragma unroll
    for (int c = 8; c < 16; ++c) {           // k-pairs (k >= 64)
      uint4 pv = p4[c];
      FDOT2(pv.x, eB[4 * (c - 8) + 0], b0);
      FDOT2(pv.y, eB[4 * (c - 8) + 1], b1);
      FDOT2(pv.z, eB[4 * (c - 8) + 2], b0);
      FDOT2(pv.w, eB[4 * (c - 8) + 3], b1);
    }
    // exact combine of the two differently-shifted halves
    const float q = (a0 + a1) + (b0 + b1) * fast_exp2(mv.y - mv.x);
    A  = fmaf(xt, LOG2E, mv.x + fast_log2(q));
    xt = xn;
  }

  // back to natural-log domain
  const float a_nat = A * LN2;

  // ---- fwd = logsumexp_j(alpha[j] + trans[END][j]) (exact max, once) ----
  __syncthreads();
  const float v = a_nat + trans[END_ID * NTAG + tid];
  float m2 = v;
  #pragma unroll
  for (int off = 1; off < 64; off <<= 1) m2 = fmaxf(m2, __shfl_xor(m2, off));
  if (lane == 0) red[wv] = m2;
  __syncthreads();
  m2 = fmaxf(red[0], red[1]);
  float s = fast_exp2((v - m2) * LOG2E);
  #pragma unroll
  for (int off = 1; off < 64; off <<= 1) s += __shfl_xor(s, off);
  __syncthreads();
  if (lane == 0) red[2 + wv] = s;
  __syncthreads();
  const float fwd = m2 + fast_log2(red[2] + red[3]) * LN2;

  // ---- gold score ----
  float g = 0.f;
  for (int i = tid; i < len; i += 128) {
    const int tn = trow[i + 1];
    const int tp = trow[i];
    g += xb[(size_t)i * NTAG + tn] + trans[tn * NTAG + tp];
  }
  #pragma unroll
  for (int off = 1; off < 64; off <<= 1) g += __shfl_xor(g, off);
  __syncthreads();
  if (lane == 0) red[wv] = g;
  __syncthreads();
  if (tid == 0) {
    const float gold = red[0] + red[1] + trans[END_ID * NTAG + trow[len]];
    ws[b] = fwd - gold;
  }
}

__global__ void reduce_kernel(const float* __restrict__ ws, float* __restrict__ out) {
  __shared__ float sm[8];
  const int tid = threadIdx.x;   // 512
  float v = ws[tid];
  #pragma unroll
  for (int off = 1; off < 64; off <<= 1) v += __shfl_xor(v, off);
  if ((tid & 63) == 0) sm[tid >> 6] = v;
  __syncthreads();
  if (tid == 0) {
    float s = 0.f;
    #pragma unroll
    for (int w = 0; w < 8; ++w) s += sm[w];
    out[0] = s * (1.0f / 512.0f);
  }
}

extern "C" void kernel_launch(void* const* d_in, const int* in_sizes, int n_in,
                              void* d_out, int out_size, void* d_ws, size_t ws_size,
                              hipStream_t stream) {
  const float* x     = (const float*)d_in[0];
  const int*   tags  = (const int*)d_in[1];
  const float* mask  = (const float*)d_in[2];
  const float* trans = (const float*)d_in[3];
  float*       ws    = (float*)d_ws;

  crf_kernel<<<NBATCH, 128, 0, stream>>>(x, tags, mask, trans, ws);
  reduce_kernel<<<1, 512, 0, stream>>>(ws, (float*)d_out);
}

// Round 8
// 385.127 us; speedup vs baseline: 1.0598x; 1.0598x over previous
//
#include <hip/hip_runtime.h>

#define NTAG 128
#define SEQ 512
#define NBATCH 512
#define END_ID 1

typedef _Float16 h2 __attribute__((ext_vector_type(2)));
typedef __fp16 fp16x2 __attribute__((ext_vector_type(2)));
typedef uint u32x32 __attribute__((ext_vector_type(32)));

#define LOG2E 1.4426950408889634f
#define LN2   0.6931471805599453f

__device__ __forceinline__ float bcast0(float v) {
  return __int_as_float(__builtin_amdgcn_readfirstlane(__float_as_int(v)));
}
__device__ __forceinline__ uint pack2(float a, float b) {
  fp16x2 h = __builtin_amdgcn_cvt_pkrtz(a, b);
  return __builtin_bit_cast(uint, h);
}
__device__ __forceinline__ h2 as_h2(uint u) { return __builtin_bit_cast(h2, u); }

__device__ __forceinline__ float fast_exp2(float x) {
#if __has_builtin(__builtin_amdgcn_exp2f)
  return __builtin_amdgcn_exp2f(x);
#else
  return exp2f(x);
#endif
}
__device__ __forceinline__ float fast_log2(float x) {
#if __has_builtin(__builtin_amdgcn_logf)
  return __builtin_amdgcn_logf(x);
#else
  return log2f(x);
#endif
}

#if __has_builtin(__builtin_amdgcn_fdot2)
#define FDOT2(pu, eu, acc) acc = __builtin_amdgcn_fdot2(as_h2(pu), as_h2(eu), acc, false)
#else
#define FDOT2(pu, eu, acc) do { h2 _p = as_h2(pu), _e = as_h2(eu); \
  acc = fmaf((float)_p.x, (float)_e.x, fmaf((float)_p.y, (float)_e.y, acc)); } while (0)
#endif

#define RL(v, l) ((uint)__builtin_amdgcn_readlane((int)(v), (l)))
#define EL(c) ((c) < 32 ? eL0[(c)] : eL1[(c) - 32])
#define EH(c) ((c) < 32 ? eH0[(c)] : eH1[(c) - 32])

// One WAVE per batch; lane l owns tags 2l, 2l+1. E' = exp2(trans*log2e) in
// 128 regs (f16 pairs). All-to-all of p via v_readlane->SGPR->dot2.
// ROUND-8 KEY CHANGE: the x-emission stream is read-once (no reuse, no
// sharing) so every step's load is an HBM MISS (~900 cyc). Rounds 4-7 all
// prefetched only 1 step ahead -> step latency pinned at ~1100-1300 cyc
// regardless of comm mechanism. Now: DEPTH-4 software pipeline on x
// (4 float2 regs, loop unrolled x4, 4 loads in flight) -> exposed latency
// ~900/4=225 cyc < ~420 cyc compute issue. Steps past len are masked
// (cndmask); load rows clamped to len (memory-safe).
__global__ __launch_bounds__(64, 1) void crf_kernel(
    const float* __restrict__ x,      // [B,S,T]
    const int*   __restrict__ tags,   // [B,S]
    const float* __restrict__ mask,   // [B,S]
    const float* __restrict__ trans,  // [T,T]
    float* __restrict__ ws)           // [B]
{
  const int b    = blockIdx.x;
  const int lane = threadIdx.x;       // 0..63

  const float* xb   = x    + (size_t)b * SEQ * NTAG;
  const float* mrow = mask + (size_t)b * SEQ;
  const int*   trow = tags + (size_t)b * SEQ;

  // ---- len = sum(mask row); mask is exact 0.0/1.0, monotonic ----
  float msum = 0.f;
  #pragma unroll
  for (int i = 0; i < SEQ / 64; ++i) msum += mrow[lane + i * 64];
  #pragma unroll
  for (int off = 1; off < 64; off <<= 1) msum += __shfl_xor(msum, off);
  const int len = (int)msum;          // in [1, 509]

  // ---- E' rows 2l (L) and 2l+1 (H): exp2(T*log2e), f16-paired ----
  u32x32 eL0, eL1, eH0, eH1;          // pair kp: [kp<32 ? *0 : *1][kp&31]
  {
    const float4* r0 = (const float4*)(trans + (size_t)(2 * lane) * NTAG);
    const float4* r1 = (const float4*)(trans + (size_t)(2 * lane + 1) * NTAG);
    #pragma unroll
    for (int k4 = 0; k4 < 16; ++k4) {
      float4 lo = r0[k4], hi = r1[k4];
      eL0[2 * k4 + 0] = pack2(fast_exp2(lo.x * LOG2E), fast_exp2(lo.y * LOG2E));
      eL0[2 * k4 + 1] = pack2(fast_exp2(lo.z * LOG2E), fast_exp2(lo.w * LOG2E));
      eH0[2 * k4 + 0] = pack2(fast_exp2(hi.x * LOG2E), fast_exp2(hi.y * LOG2E));
      eH0[2 * k4 + 1] = pack2(fast_exp2(hi.z * LOG2E), fast_exp2(hi.w * LOG2E));
    }
    #pragma unroll
    for (int k4 = 16; k4 < 32; ++k4) {
      float4 lo = r0[k4], hi = r1[k4];
      eL1[2 * (k4 - 16) + 0] = pack2(fast_exp2(lo.x * LOG2E), fast_exp2(lo.y * LOG2E));
      eL1[2 * (k4 - 16) + 1] = pack2(fast_exp2(lo.z * LOG2E), fast_exp2(lo.w * LOG2E));
      eH1[2 * (k4 - 16) + 0] = pack2(fast_exp2(hi.x * LOG2E), fast_exp2(hi.y * LOG2E));
      eH1[2 * (k4 - 16) + 1] = pack2(fast_exp2(hi.z * LOG2E), fast_exp2(hi.w * LOG2E));
    }
  }

  // log2-domain alpha
  float A_lo = (lane == 0) ? 0.f : -14427.f;   // -1e4 * log2e  (START_ID=0)
  float A_hi = -14427.f;

  const float2* xrow = (const float2*)xb;      // row t: xrow[t*64 + lane]
  // depth-4 prefetch pipeline (rows 0..3 always in-bounds: SEQ=512)
  float2 xf0 = xrow[0 * 64 + lane];
  float2 xf1 = xrow[1 * 64 + lane];
  float2 xf2 = xrow[2 * 64 + lane];
  float2 xf3 = xrow[3 * 64 + lane];

#define CRF_STEP(XF, S)                                                       \
  {                                                                           \
    const int g = t + (S);                                                    \
    const float M = bcast0(A_lo);                                             \
    const uint pk = pack2(fminf(fast_exp2(A_lo - M), 60000.f),                \
                          fminf(fast_exp2(A_hi - M), 60000.f));               \
    const float2 xt = XF;                                                     \
    XF = xrow[(size_t)min(g + 4, len) * 64 + lane]; /* refill, 4 in flight */ \
    float qL0 = 0.f, qL1 = 0.f, qL2 = 0.f, qL3 = 0.f;                         \
    float qH0 = 0.f, qH1 = 0.f, qH2 = 0.f, qH3 = 0.f;                         \
    _Pragma("unroll")                                                         \
    for (int gg = 0; gg < 64; gg += 8) {                                      \
      const uint s0 = RL(pk, gg + 0), s1 = RL(pk, gg + 1);                    \
      const uint s2 = RL(pk, gg + 2), s3 = RL(pk, gg + 3);                    \
      const uint s4 = RL(pk, gg + 4), s5 = RL(pk, gg + 5);                    \
      const uint s6 = RL(pk, gg + 6), s7 = RL(pk, gg + 7);                    \
      FDOT2(s0, EL(gg + 0), qL0); FDOT2(s0, EH(gg + 0), qH0);                 \
      FDOT2(s1, EL(gg + 1), qL1); FDOT2(s1, EH(gg + 1), qH1);                 \
      FDOT2(s2, EL(gg + 2), qL2); FDOT2(s2, EH(gg + 2), qH2);                 \
      FDOT2(s3, EL(gg + 3), qL3); FDOT2(s3, EH(gg + 3), qH3);                 \
      FDOT2(s4, EL(gg + 4), qL0); FDOT2(s4, EH(gg + 4), qH0);                 \
      FDOT2(s5, EL(gg + 5), qL1); FDOT2(s5, EH(gg + 5), qH1);                 \
      FDOT2(s6, EL(gg + 6), qL2); FDOT2(s6, EH(gg + 6), qH2);                 \
      FDOT2(s7, EL(gg + 7), qL3); FDOT2(s7, EH(gg + 7), qH3);                 \
    }                                                                         \
    const float qL = (qL0 + qL1) + (qL2 + qL3);                               \
    const float qH = (qH0 + qH1) + (qH2 + qH3);                               \
    const float nL = fmaf(xt.x, LOG2E, M + fast_log2(qL));                    \
    const float nH = fmaf(xt.y, LOG2E, M + fast_log2(qH));                    \
    const bool act = (g < len);                                               \
    A_lo = act ? nL : A_lo;                                                   \
    A_hi = act ? nH : A_hi;                                                   \
  }

  for (int t = 0; t < len; t += 4) {
    CRF_STEP(xf0, 0)
    CRF_STEP(xf1, 1)
    CRF_STEP(xf2, 2)
    CRF_STEP(xf3, 3)
  }
#undef CRF_STEP

  // back to natural-log domain
  const float a_lo = A_lo * LN2;
  const float a_hi = A_hi * LN2;

  // ---- fwd = logsumexp_j(alpha[j] + trans[END][j]) (exact max, once) ----
  const float2 te = ((const float2*)(trans + END_ID * NTAG))[lane];
  const float v_lo = a_lo + te.x;
  const float v_hi = a_hi + te.y;
  float m2 = fmaxf(v_lo, v_hi);
  #pragma unroll
  for (int off = 1; off < 64; off <<= 1) m2 = fmaxf(m2, __shfl_xor(m2, off));
  float s = fast_exp2((v_lo - m2) * LOG2E) + fast_exp2((v_hi - m2) * LOG2E);
  #pragma unroll
  for (int off = 1; off < 64; off <<= 1) s += __shfl_xor(s, off);
  const float fwd = m2 + fast_log2(s) * LN2;

  // ---- gold score ----
  float g = 0.f;
  for (int i = lane; i < len; i += 64) {
    const int tn = trow[i + 1];
    const int tp = trow[i];
    g += xb[(size_t)i * NTAG + tn] + trans[tn * NTAG + tp];
  }
  #pragma unroll
  for (int off = 1; off < 64; off <<= 1) g += __shfl_xor(g, off);

  if (lane == 0) {
    const float gold = g + trans[END_ID * NTAG + trow[len]];
    ws[b] = fwd - gold;
  }
}

__global__ void reduce_kernel(const float* __restrict__ ws, float* __restrict__ out) {
  __shared__ float sm[8];
  const int tid = threadIdx.x;   // 512
  float v = ws[tid];
  #pragma unroll
  for (int off = 1; off < 64; off <<= 1) v += __shfl_xor(v, off);
  if ((tid & 63) == 0) sm[tid >> 6] = v;
  __syncthreads();
  if (tid == 0) {
    float s = 0.f;
    #pragma unroll
    for (int w = 0; w < 8; ++w) s += sm[w];
    out[0] = s * (1.0f / 512.0f);
  }
}

extern "C" void kernel_launch(void* const* d_in, const int* in_sizes, int n_in,
                              void* d_out, int out_size, void* d_ws, size_t ws_size,
                              hipStream_t stream) {
  const float* x     = (const float*)d_in[0];
  const int*   tags  = (const int*)d_in[1];
  const float* mask  = (const float*)d_in[2];
  const float* trans = (const float*)d_in[3];
  float*       ws    = (float*)d_ws;

  crf_kernel<<<NBATCH, 64, 0, stream>>>(x, tags, mask, trans, ws);
  reduce_kernel<<<1, 512, 0, stream>>>(ws, (float*)d_out);
}